// Round 1
// baseline (13041.289 us; speedup 1.0000x reference)
//
#include <hip/hip_runtime.h>
#include <cmath>

constexpr int SEQ = 64;    // sequence length
constexpr int NB  = 128;   // batch
constexpr int H   = 256;   // hidden
constexpr int DIN = 128;   // composed token dim
constexpr int DE  = 256;   // word emb dim
constexpr int NA  = 64;    // actions
constexpr int S1  = 41;    // STACK_SIZE+1
constexpr int MS  = 100;   // max steps
constexpr int G4  = 1024;  // 4*H

__device__ __forceinline__ float sigf(float x){ return 1.0f/(1.0f+expf(-x)); }

// hist_xz[a][r] = hist_Wih[r,:] . action_emb[a,:] + hist_bih[r] + hist_bhh[r]
__global__ void hist_proj_kernel(const float* __restrict__ Wih,
                                 const float* __restrict__ bih,
                                 const float* __restrict__ bhh,
                                 const float* __restrict__ aemb,
                                 float* __restrict__ out){
  int a = blockIdx.x, t = threadIdx.x;
  __shared__ float e[64];
  if (t < 64) e[t] = aemb[a*64 + t];
  __syncthreads();
  for (int r = t; r < G4; r += blockDim.x){
    const float* w = Wih + r*64;
    float acc = bih[r] + bhh[r];
    #pragma unroll
    for (int k = 0; k < 64; k += 4)
      acc += w[k]*e[k] + w[k+1]*e[k+1] + w[k+2]*e[k+2] + w[k+3]*e[k+3];
    out[a*G4 + r] = acc;
  }
}

// One workgroup per batch element; 512 threads.
__global__ __launch_bounds__(512)
void parser_kernel(const int* __restrict__ tokens,
                   const float* __restrict__ word_emb,
                   const float* __restrict__ compose_W,
                   const float* __restrict__ compose_b,
                   const float* __restrict__ h0,
                   const float* __restrict__ c0,
                   const float* __restrict__ pb_Wih,
                   const float* __restrict__ pb_Whh,
                   const float* __restrict__ pb_bih,
                   const float* __restrict__ pb_bhh,
                   const float* __restrict__ st_Wih,
                   const float* __restrict__ st_Whh,
                   const float* __restrict__ st_bih,
                   const float* __restrict__ st_bhh,
                   const float* __restrict__ hist_Whh,
                   const float* __restrict__ sum_W,
                   const float* __restrict__ sum_b,
                   const float* __restrict__ act_W,
                   const float* __restrict__ act_b,
                   const int* __restrict__ stack_map,
                   const int* __restrict__ buffer_map,
                   const float* __restrict__ histxz,
                   float* __restrict__ pb_zx,   // [B][64][1024]
                   float* __restrict__ st_zx,   // [B][65][1024] (row 64 = bias only)
                   float* __restrict__ bufh,    // [B][64][256]
                   float* __restrict__ scst,    // [B][41][256] stack c in global
                   float* __restrict__ out)     // [100][128][64]
{
  // LDS unions (total ~60KB, under the 64KB static limit):
  __shared__ __align__(16) float u0[12288];  // P0: tok[64][128] + emb_stage[16][256] ; main: stack_h[41][256]
  __shared__ __align__(16) float u1[2048];   // cat/psum/summary/logits  |  z_st[1024], z_hist[1024] | P1 z
  __shared__ __align__(16) float bstate[H];
  __shared__ __align__(16) float ahl[H];
  __shared__ __align__(16) float acl[H];
  __shared__ __align__(16) float h0l[H];
  __shared__ int ctl[12];

  const int b   = blockIdx.x;
  const int tid = threadIdx.x;

  float* tokl   = u0;              // [64][128]
  float* embs   = u0 + SEQ*DIN;    // [16][256]
  float* stackh = u0;              // [41][256]
  float* catv   = u1;              // 768
  float* psum   = u1 + 768;        // [2][256]
  float* summ   = u1 + 1280;       // 256
  float* lg     = u1 + 1536;       // 64
  float* zst    = u1;              // 1024
  float* zhi    = u1 + 1024;       // 1024

  if (tid < H) h0l[tid] = h0[tid];
  __syncthreads();

  // ---------------- P0a: token composition: tok[t] = relu(W_c @ emb[tokens[t,b]] + b_c)
  for (int tile = 0; tile < 4; ++tile){
    for (int j = tid >> 8; j < 16; j += 2){
      int tt = tile*16 + j;
      int id = tokens[tt*NB + b];
      embs[j*DE + (tid & 255)] = word_emb[(size_t)id*DE + (tid & 255)];
    }
    __syncthreads();
    int d = tid & 127, tg = tid >> 7;
    const float4* wr = (const float4*)(compose_W + d*DE);
    const float4* e0 = (const float4*)(embs + (tg     )*DE);
    const float4* e1 = (const float4*)(embs + (tg +  4)*DE);
    const float4* e2 = (const float4*)(embs + (tg +  8)*DE);
    const float4* e3 = (const float4*)(embs + (tg + 12)*DE);
    float a0 = compose_b[d], a1 = a0, a2 = a0, a3 = a0;
    for (int c = 0; c < DE/4; ++c){
      float4 w = wr[c];
      float4 v0 = e0[c], v1 = e1[c], v2 = e2[c], v3 = e3[c];
      a0 += w.x*v0.x + w.y*v0.y + w.z*v0.z + w.w*v0.w;
      a1 += w.x*v1.x + w.y*v1.y + w.z*v1.z + w.w*v1.w;
      a2 += w.x*v2.x + w.y*v2.y + w.z*v2.z + w.w*v2.w;
      a3 += w.x*v3.x + w.y*v3.y + w.z*v3.z + w.w*v3.w;
    }
    __syncthreads();   // emb reads done before next tile restages
    tokl[(tile*16 + tg     )*DIN + d] = fmaxf(a0, 0.f);
    tokl[(tile*16 + tg +  4)*DIN + d] = fmaxf(a1, 0.f);
    tokl[(tile*16 + tg +  8)*DIN + d] = fmaxf(a2, 0.f);
    tokl[(tile*16 + tg + 12)*DIN + d] = fmaxf(a3, 0.f);
  }
  __syncthreads();

  // ---------------- P0b: input projections zx = Wih @ tok + (bih+bhh), biases folded
  for (int m = 0; m < 2; ++m){
    const float* Wih = m ? st_Wih : pb_Wih;
    const float* bi1 = m ? st_bih : pb_bih;
    const float* bi2 = m ? st_bhh : pb_bhh;
    float* zx = m ? (st_zx + (size_t)b*(SEQ+1)*G4) : (pb_zx + (size_t)b*SEQ*G4);
    for (int half = 0; half < 2; ++half){
      int r = tid + half*512;
      const float4* wr = (const float4*)(Wih + (size_t)r*DIN);
      float bias = bi1[r] + bi2[r];
      for (int t2b = 0; t2b < SEQ; t2b += 32){
        float acc[32];
        #pragma unroll
        for (int q = 0; q < 32; ++q) acc[q] = 0.f;
        for (int c = 0; c < DIN/4; ++c){
          float4 w = wr[c];
          #pragma unroll
          for (int q = 0; q < 32; ++q){
            float4 tk = ((const float4*)(tokl + (t2b + q)*DIN))[c];
            acc[q] += w.x*tk.x + w.y*tk.y + w.z*tk.z + w.w*tk.w;
          }
        }
        #pragma unroll
        for (int q = 0; q < 32; ++q)
          zx[(size_t)(t2b + q)*G4 + r] = acc[q] + bias;
      }
      if (m) zx[(size_t)SEQ*G4 + r] = bias;   // row 64 = zero-input (bias only)
    }
  }
  __syncthreads();

  // ---------------- P1: pre-buffer LSTM over reversed tokens; bufh[k] = h after k+1 steps
  if (tid < H){ ahl[tid] = h0l[tid]; acl[tid] = c0[tid]; }   // reuse ahl/acl as (h,c)
  __syncthreads();
  for (int k = 0; k < SEQ; ++k){
    int tt = SEQ - 1 - k;
    const float* zx = pb_zx + ((size_t)b*SEQ + tt)*G4;
    #pragma unroll
    for (int half = 0; half < 2; ++half){
      int r = tid + half*512;
      const float4* wr = (const float4*)(pb_Whh + (size_t)r*H);
      const float4* hv = (const float4*)ahl;
      float a0 = 0.f, a1 = 0.f;
      for (int c = 0; c < H/8; ++c){
        float4 w0 = wr[2*c], w1 = wr[2*c+1];
        float4 v0 = hv[2*c], v1 = hv[2*c+1];
        a0 += w0.x*v0.x + w0.y*v0.y + w0.z*v0.z + w0.w*v0.w;
        a1 += w1.x*v1.x + w1.y*v1.y + w1.z*v1.z + w1.w*v1.w;
      }
      u1[r] = zx[r] + a0 + a1;
    }
    __syncthreads();
    if (tid < H){
      float gi = u1[tid], gf = u1[H+tid], gg = u1[2*H+tid], go = u1[3*H+tid];
      float c2 = sigf(gf)*acl[tid] + sigf(gi)*tanhf(gg);
      float h2 = sigf(go)*tanhf(c2);
      acl[tid] = c2; ahl[tid] = h2;
      bufh[((size_t)b*SEQ + k)*H + tid] = h2;
    }
    __syncthreads();
  }

  // ---------------- main init
  for (int i = tid; i < S1*H; i += 512) stackh[i] = 0.f;
  if (tid < H) bstate[tid] = ahl[tid];          // b_state = buf_h[63]
  __syncthreads();
  if (tid < H) stackh[tid] = h0l[tid];          // stack_h[0] = h0
  {
    float* cst = scst + (size_t)b*S1*H;
    for (int i = tid; i < S1*H; i += 512) cst[i] = (i < H) ? c0[i] : 0.f;
  }
  if (tid < H){ ahl[tid] = h0l[tid]; acl[tid] = c0[tid]; }   // hist LSTM state
  if (tid == 0){ ctl[0] = 0; ctl[1] = SEQ; ctl[2] = SEQ - 1; } // spos, bpos, sin_idx
  __syncthreads();

  // ---------------- main parser loop
  for (int step = 0; step < MS; ++step){
    const int spos = ctl[0], bposc = ctl[1], sinc = ctl[2];

    // cat = [stack_top, b_state, ah]
    if (tid < H){ catv[tid] = stackh[spos*H + tid]; catv[2*H + tid] = ahl[tid]; }
    else        { catv[H + (tid - H)] = bstate[tid - H]; }
    __syncthreads();

    // summary = relu(sum_W @ cat + sum_b) — 512 threads: (row, col-half)
    {
      int r = tid & 255, cg = tid >> 8;
      const float4* wr = (const float4*)(sum_W + (size_t)r*768 + cg*384);
      const float4* cv = (const float4*)(catv + cg*384);
      float a0 = 0.f, a1 = 0.f;
      for (int c = 0; c < 384/8; ++c){
        float4 w0 = wr[2*c], w1 = wr[2*c+1];
        float4 v0 = cv[2*c], v1 = cv[2*c+1];
        a0 += w0.x*v0.x + w0.y*v0.y + w0.z*v0.z + w0.w*v0.w;
        a1 += w1.x*v1.x + w1.y*v1.y + w1.z*v1.z + w1.w*v1.w;
      }
      psum[cg*256 + r] = a0 + a1;
    }
    __syncthreads();
    if (tid < 256) summ[tid] = fmaxf(psum[tid] + psum[256 + tid] + sum_b[tid], 0.f);
    __syncthreads();

    // logits
    if (tid < 64){
      const float4* wr = (const float4*)(act_W + tid*256);
      const float4* sv = (const float4*)summ;
      float a0 = 0.f;
      for (int c = 0; c < 64; ++c){
        float4 w = wr[c], v = sv[c];
        a0 += w.x*v.x + w.y*v.y + w.z*v.z + w.w*v.w;
      }
      lg[tid] = a0 + act_b[tid];
    }
    __syncthreads();

    // wave 0: log_softmax + store + argmax + control
    if (tid < 64){
      float v = lg[tid];
      float mx = v;
      #pragma unroll
      for (int o = 32; o > 0; o >>= 1) mx = fmaxf(mx, __shfl_xor(mx, o));
      float ex = expf(v - mx), sm = ex;
      #pragma unroll
      for (int o = 32; o > 0; o >>= 1) sm += __shfl_xor(sm, o);
      out[(((size_t)step*NB) + b)*NA + tid] = v - mx - logf(sm);
      float bv = v; int bi = tid;     // argmax, first index wins on ties
      #pragma unroll
      for (int o = 32; o > 0; o >>= 1){
        float ov = __shfl_xor(bv, o); int oi = __shfl_xor(bi, o);
        if (ov > bv || (ov == bv && oi < bi)){ bv = ov; bi = oi; }
      }
      if (tid == 0){
        int a = bi;
        int sop = stack_map[a], bop = buffer_map[a];
        if (spos == 0 && sop == -1) sop = 0;
        if (spos >= S1 - 1 && sop == 1) sop = 0;
        if (bposc == 0 && bop == -1) bop = 0;
        int push  = (sop == 1) ? 1 : 0;
        int widx  = (spos + 1 < S1 - 1) ? spos + 1 : S1 - 1;
        int sposn = spos + sop;
        int bposn = bposc + bop;
        int ne    = (bposn > 0) ? 1 : 0;
        int gidx  = bposn - 1; if (gidx < 0) gidx = 0; if (gidx > SEQ - 1) gidx = SEQ - 1;
        ctl[3] = a; ctl[4] = push; ctl[5] = widx; ctl[6] = sposn;
        ctl[7] = bposn; ctl[8] = ne; ctl[9] = gidx;
      }
    }
    __syncthreads();

    // z_st = st_zx[sin] + st_Whh @ stack_top ; z_hist = hist_xz[a] + hist_Whh @ ah
    {
      const int a = ctl[3];
      const float* stz = st_zx + ((size_t)b*(SEQ+1) + sinc)*G4;
      const float* hxz = histxz + (size_t)a*G4;
      const float4* sv = (const float4*)(stackh + spos*H);
      const float4* av = (const float4*)ahl;
      #pragma unroll
      for (int half = 0; half < 2; ++half){
        int r = tid + half*512;
        {
          const float4* wr = (const float4*)(st_Whh + (size_t)r*H);
          float a0 = 0.f, a1 = 0.f;
          for (int c = 0; c < H/8; ++c){
            float4 w0 = wr[2*c], w1 = wr[2*c+1];
            float4 v0 = sv[2*c], v1 = sv[2*c+1];
            a0 += w0.x*v0.x + w0.y*v0.y + w0.z*v0.z + w0.w*v0.w;
            a1 += w1.x*v1.x + w1.y*v1.y + w1.z*v1.z + w1.w*v1.w;
          }
          zst[r] = stz[r] + a0 + a1;
        }
        {
          const float4* wr = (const float4*)(hist_Whh + (size_t)r*H);
          float a0 = 0.f, a1 = 0.f;
          for (int c = 0; c < H/8; ++c){
            float4 w0 = wr[2*c], w1 = wr[2*c+1];
            float4 v0 = av[2*c], v1 = av[2*c+1];
            a0 += w0.x*v0.x + w0.y*v0.y + w0.z*v0.z + w0.w*v0.w;
            a1 += w1.x*v1.x + w1.y*v1.y + w1.z*v1.z + w1.w*v1.w;
          }
          zhi[r] = hxz[r] + a0 + a1;
        }
      }
    }
    __syncthreads();

    // gates + state commit
    {
      const int push = ctl[4], widx = ctl[5], sposn = ctl[6];
      const int ne = ctl[8], gidx = ctl[9];
      if (tid < H){
        float gi = zst[tid], gf = zst[H+tid], gg = zst[2*H+tid], go = zst[3*H+tid];
        float ctop = scst[((size_t)b*S1 + spos)*H + tid];
        float c2 = sigf(gf)*ctop + sigf(gi)*tanhf(gg);
        float h2 = sigf(go)*tanhf(c2);
        if (push){
          stackh[widx*H + tid] = h2;
          scst[((size_t)b*S1 + widx)*H + tid] = c2;
        }
        bstate[tid] = ne ? bufh[((size_t)b*SEQ + gidx)*H + tid] : h0l[tid];
      } else {
        int hh = tid - H;
        float gi = zhi[hh], gf = zhi[H+hh], gg = zhi[2*H+hh], go = zhi[3*H+hh];
        float c2 = sigf(gf)*acl[hh] + sigf(gi)*tanhf(gg);
        float h2 = sigf(go)*tanhf(c2);
        acl[hh] = c2; ahl[hh] = h2;
      }
      if (tid == 0){
        ctl[0] = sposn; ctl[1] = ctl[7]; ctl[2] = ne ? gidx : SEQ;
      }
      (void)sposn;
    }
    __syncthreads();
  }
}

extern "C" void kernel_launch(void* const* d_in, const int* in_sizes, int n_in,
                              void* d_out, int out_size, void* d_ws, size_t ws_size,
                              hipStream_t stream){
  (void)in_sizes; (void)n_in; (void)out_size; (void)ws_size;
  const int*   tokens    = (const int*)  d_in[0];
  const float* word_emb  = (const float*)d_in[1];
  const float* compose_W = (const float*)d_in[2];
  const float* compose_b = (const float*)d_in[3];
  const float* h0        = (const float*)d_in[4];
  const float* c0        = (const float*)d_in[5];
  const float* pb_Wih    = (const float*)d_in[6];
  const float* pb_Whh    = (const float*)d_in[7];
  const float* pb_bih    = (const float*)d_in[8];
  const float* pb_bhh    = (const float*)d_in[9];
  const float* st_Wih    = (const float*)d_in[10];
  const float* st_Whh    = (const float*)d_in[11];
  const float* st_bih    = (const float*)d_in[12];
  const float* st_bhh    = (const float*)d_in[13];
  const float* hist_Wih  = (const float*)d_in[14];
  const float* hist_Whh  = (const float*)d_in[15];
  const float* hist_bih  = (const float*)d_in[16];
  const float* hist_bhh  = (const float*)d_in[17];
  const float* sum_W     = (const float*)d_in[18];
  const float* sum_b     = (const float*)d_in[19];
  const float* act_W     = (const float*)d_in[20];
  const float* act_b     = (const float*)d_in[21];
  const float* action_emb= (const float*)d_in[22];
  const int*   stack_map = (const int*)  d_in[23];
  const int*   buffer_map= (const int*)  d_in[24];

  float* ws     = (float*)d_ws;
  float* pb_zx  = ws;                                  // 128*64*1024
  float* st_zx  = pb_zx + (size_t)NB*SEQ*G4;           // 128*65*1024
  float* bufh   = st_zx + (size_t)NB*(SEQ+1)*G4;       // 128*64*256
  float* scst   = bufh  + (size_t)NB*SEQ*H;            // 128*41*256
  float* histxz = scst  + (size_t)NB*S1*H;             // 64*1024

  hist_proj_kernel<<<dim3(NA), dim3(256), 0, stream>>>(hist_Wih, hist_bih, hist_bhh,
                                                       action_emb, histxz);
  parser_kernel<<<dim3(NB), dim3(512), 0, stream>>>(tokens, word_emb, compose_W, compose_b,
      h0, c0, pb_Wih, pb_Whh, pb_bih, pb_bhh, st_Wih, st_Whh, st_bih, st_bhh,
      hist_Whh, sum_W, sum_b, act_W, act_b, stack_map, buffer_map,
      histxz, pb_zx, st_zx, bufh, scst, (float*)d_out);
}

// Round 2
// 4794.630 us; speedup vs baseline: 2.7200x; 2.7200x over previous
//
#include <hip/hip_runtime.h>
#include <cmath>

constexpr int SEQ = 64;    // sequence length
constexpr int NB  = 128;   // batch
constexpr int H   = 256;   // hidden
constexpr int DIN = 128;   // composed token dim
constexpr int DE  = 256;   // word emb dim
constexpr int NA  = 64;    // actions
constexpr int S1  = 41;    // STACK_SIZE+1
constexpr int MS  = 100;   // max steps
constexpr int G4  = 1024;  // 4*H

__device__ __forceinline__ float sigf(float x){ return 1.0f/(1.0f+expf(-x)); }

// ---------------- transpose: in [R][C] -> out [C][R]
__global__ void transpose_k(const float* __restrict__ in, float* __restrict__ out,
                            int R, int C){
  __shared__ float t[32][33];
  int bx = blockIdx.x*32, by = blockIdx.y*32;
  int x = threadIdx.x, y = threadIdx.y;   // block 32x8
  #pragma unroll
  for (int j = 0; j < 32; j += 8)
    t[y+j][x] = in[(size_t)(by+y+j)*C + bx + x];
  __syncthreads();
  #pragma unroll
  for (int j = 0; j < 32; j += 8)
    out[(size_t)(bx+y+j)*R + by + x] = t[x][y+j];
}

// hist_xz[a][r] = hist_Wih[r,:] . action_emb[a,:] + hist_bih[r] + hist_bhh[r]
__global__ void hist_proj_kernel(const float* __restrict__ Wih,
                                 const float* __restrict__ bih,
                                 const float* __restrict__ bhh,
                                 const float* __restrict__ aemb,
                                 float* __restrict__ out){
  int a = blockIdx.x, t = threadIdx.x;
  __shared__ float e[64];
  if (t < 64) e[t] = aemb[a*64 + t];
  __syncthreads();
  for (int r = t; r < G4; r += blockDim.x){
    const float* w = Wih + r*64;
    float acc = bih[r] + bhh[r];
    #pragma unroll
    for (int k = 0; k < 64; k += 4)
      acc += w[k]*e[k] + w[k+1]*e[k+1] + w[k+2]*e[k+2] + w[k+3]*e[k+3];
    out[a*G4 + r] = acc;
  }
}

// One workgroup per batch element; 512 threads. All weight matvecs read
// TRANSPOSED weights: thread owns 4 (or 2) consecutive output rows, inner
// loop over c does a lane-contiguous float4/float2 load + LDS broadcast.
__global__ __launch_bounds__(512, 2)
void parser_kernel(const int* __restrict__ tokens,
                   const float* __restrict__ word_emb,
                   const float* __restrict__ Wt_cmp,   // [256][128]
                   const float* __restrict__ compose_b,
                   const float* __restrict__ h0,
                   const float* __restrict__ c0,
                   const float* __restrict__ Wt_pbih,  // [128][1024]
                   const float* __restrict__ Wt_pb,    // [256][1024]
                   const float* __restrict__ pb_bih,
                   const float* __restrict__ pb_bhh,
                   const float* __restrict__ Wt_stih,  // [128][1024]
                   const float* __restrict__ Wt_st,    // [256][1024]
                   const float* __restrict__ st_bih,
                   const float* __restrict__ st_bhh,
                   const float* __restrict__ Wt_hi,    // [256][1024]
                   const float* __restrict__ Wt_sum,   // [768][256]
                   const float* __restrict__ sum_b,
                   const float* __restrict__ Wt_act,   // [256][64]
                   const float* __restrict__ act_b,
                   const int* __restrict__ stack_map,
                   const int* __restrict__ buffer_map,
                   const float* __restrict__ histxz,   // [64][1024]
                   float* __restrict__ pb_zx,   // [B][64][1024]
                   float* __restrict__ st_zx,   // [B][65][1024] (row 64 = bias only)
                   float* __restrict__ bufh,    // [B][64][256]
                   float* __restrict__ scst,    // [B][41][256] stack c
                   float* __restrict__ out)     // [100][128][64]
{
  __shared__ __align__(16) float u0[12288];  // P0: tok[64][128] + emb[16][256]; main: stack_h[41][256]
  __shared__ __align__(16) float u1[2048];   // f64 psum[4][256] | z_st[1024]+z_hist[1024] | pb z
  __shared__ __align__(16) float bstate[H];
  __shared__ __align__(16) float ahl[H];
  __shared__ __align__(16) float acl[H];
  __shared__ __align__(16) float h0l[H];
  __shared__ __align__(16) float summ[H];
  __shared__ int ctl[12];

  const int b   = blockIdx.x;
  const int tid = threadIdx.x;

  float* tokl   = u0;              // [64][128]
  float* embs   = u0 + SEQ*DIN;    // [16][256]
  float* stackh = u0;              // [41][256]

  if (tid < H) h0l[tid] = h0[tid];
  __syncthreads();

  // ---------------- P0a: tok[t] = relu(W_c @ emb[tokens[t,b]] + b_c), coalesced via Wt_cmp
  {
    const int d = tid & 127, tb = tid >> 7;
    const float cb = compose_b[d];
    for (int pass = 0; pass < 4; ++pass){
      for (int j = tid >> 8; j < 16; j += 2){
        int tt = pass*16 + j;
        int id = tokens[tt*NB + b];
        embs[j*DE + (tid & 255)] = word_emb[(size_t)id*DE + (tid & 255)];
      }
      __syncthreads();
      float a0 = 0.f, a1 = 0.f, a2 = 0.f, a3 = 0.f;
      const float* eb = embs + (tb*4)*DE;
      for (int c = 0; c < DE; ++c){
        float w = Wt_cmp[c*DIN + d];
        a0 += w*eb[c]; a1 += w*eb[DE + c]; a2 += w*eb[2*DE + c]; a3 += w*eb[3*DE + c];
      }
      int t0 = pass*16 + tb*4;
      tokl[(t0    )*DIN + d] = fmaxf(a0 + cb, 0.f);
      tokl[(t0 + 1)*DIN + d] = fmaxf(a1 + cb, 0.f);
      tokl[(t0 + 2)*DIN + d] = fmaxf(a2 + cb, 0.f);
      tokl[(t0 + 3)*DIN + d] = fmaxf(a3 + cb, 0.f);
      __syncthreads();   // embs reads done before next pass restages
    }
  }

  // ---------------- P0b: zx = Wih @ tok + (bih+bhh).  threads 0-255: pb, 256-511: st.
  {
    const int m = tid >> 8, lt = tid & 255;
    const float* Wt  = m ? Wt_stih : Wt_pbih;           // [128][1024]
    float*       zxb = m ? (st_zx + (size_t)b*(SEQ+1)*G4) : (pb_zx + (size_t)b*SEQ*G4);
    const float* bA  = m ? st_bih : pb_bih;
    const float* bB  = m ? st_bhh : pb_bhh;
    float4 x1 = ((const float4*)bA)[lt], x2 = ((const float4*)bB)[lt];
    float bx = x1.x + x2.x, by = x1.y + x2.y, bz = x1.z + x2.z, bw = x1.w + x2.w;
    for (int blk = 0; blk < 4; ++blk){
      float ax[16], ay[16], az[16], aw[16];
      #pragma unroll
      for (int t = 0; t < 16; ++t){ ax[t]=0.f; ay[t]=0.f; az[t]=0.f; aw[t]=0.f; }
      const float* tb = tokl + (blk*16)*DIN;
      for (int c = 0; c < DIN; ++c){
        float4 w = ((const float4*)(Wt + (size_t)c*G4))[lt];
        #pragma unroll
        for (int t = 0; t < 16; ++t){
          float x = tb[t*DIN + c];
          ax[t] += w.x*x; ay[t] += w.y*x; az[t] += w.z*x; aw[t] += w.w*x;
        }
      }
      #pragma unroll
      for (int t = 0; t < 16; ++t){
        float4 r = make_float4(ax[t]+bx, ay[t]+by, az[t]+bz, aw[t]+bw);
        ((float4*)(zxb + (size_t)(blk*16 + t)*G4))[lt] = r;
      }
    }
    if (m) ((float4*)(zxb + (size_t)SEQ*G4))[lt] = make_float4(bx, by, bz, bw);
  }
  __syncthreads();

  // ---------------- P1: pre-buffer LSTM over reversed tokens (coalesced Wt_pb)
  if (tid < H){ ahl[tid] = h0l[tid]; acl[tid] = c0[tid]; }   // (h,c)
  __syncthreads();
  for (int k = 0; k < SEQ; ++k){
    int tt = SEQ - 1 - k;
    {
      float a0 = 0.f, a1 = 0.f;
      for (int c = 0; c < H; ++c){
        float2 w = ((const float2*)(Wt_pb + (size_t)c*G4))[tid];
        float x = ahl[c];
        a0 += w.x*x; a1 += w.y*x;
      }
      float2 zx = ((const float2*)(pb_zx + ((size_t)b*SEQ + tt)*G4))[tid];
      ((float2*)u1)[tid] = make_float2(a0 + zx.x, a1 + zx.y);
    }
    __syncthreads();
    if (tid < H){
      float gi = u1[tid], gf = u1[H+tid], gg = u1[2*H+tid], go = u1[3*H+tid];
      float c2 = sigf(gf)*acl[tid] + sigf(gi)*tanhf(gg);
      float h2 = sigf(go)*tanhf(c2);
      acl[tid] = c2; ahl[tid] = h2;
      bufh[((size_t)b*SEQ + k)*H + tid] = h2;
    }
    __syncthreads();
  }

  // ---------------- main init
  for (int i = tid; i < S1*H; i += 512) stackh[i] = 0.f;
  if (tid < H) bstate[tid] = ahl[tid];          // b_state = buf_h[63]
  __syncthreads();
  if (tid < H) stackh[tid] = h0l[tid];          // stack_h[0] = h0
  {
    float* cst = scst + (size_t)b*S1*H;
    for (int i = tid; i < S1*H; i += 512) cst[i] = (i < H) ? c0[i] : 0.f;
  }
  if (tid < H){ ahl[tid] = h0l[tid]; acl[tid] = c0[tid]; }   // hist LSTM state
  if (tid == 0){ ctl[0] = 0; ctl[1] = SEQ; ctl[2] = SEQ - 1; } // spos, bpos, sin_idx
  __syncthreads();

  // ---------------- main parser loop
  for (int step = 0; step < MS; ++step){
    const int spos = ctl[0], bposc = ctl[1], sinc = ctl[2];

    // B: summary partials, f64 accumulation, 4-way c-split (192 c each)
    {
      const int lt = tid & 127, cg = tid >> 7;
      double a0 = 0.0, a1 = 0.0;
      const int cbeg = cg*192, cend = cbeg + 192;
      for (int c = cbeg; c < cend; ++c){
        float2 w = ((const float2*)(Wt_sum + (size_t)c*H))[lt];
        float xc = (c < 256) ? stackh[spos*H + c]
                 : (c < 512) ? bstate[c - 256] : ahl[c - 512];
        double dx = (double)xc;
        a0 += (double)w.x * dx; a1 += (double)w.y * dx;
      }
      double* pd = (double*)u1;
      pd[cg*H + lt*2    ] = a0;
      pd[cg*H + lt*2 + 1] = a1;
    }
    __syncthreads();
    if (tid < H){
      const double* pd = (const double*)u1;
      double s = pd[tid] + pd[H+tid] + pd[2*H+tid] + pd[3*H+tid] + (double)sum_b[tid];
      summ[tid] = fmaxf((float)s, 0.f);
    }
    __syncthreads();

    // C: logits (f64 acc, coalesced Wt_act) + log_softmax + argmax + control (wave 0)
    if (tid < 64){
      double acc = 0.0;
      for (int c = 0; c < H; ++c)
        acc += (double)Wt_act[c*NA + tid] * (double)summ[c];
      float v = (float)(acc + (double)act_b[tid]);
      float mx = v;
      #pragma unroll
      for (int o = 32; o > 0; o >>= 1) mx = fmaxf(mx, __shfl_xor(mx, o));
      float ex = expf(v - mx), sm = ex;
      #pragma unroll
      for (int o = 32; o > 0; o >>= 1) sm += __shfl_xor(sm, o);
      out[(((size_t)step*NB) + b)*NA + tid] = v - mx - logf(sm);
      float bv = v; int bi = tid;     // argmax, first index wins on ties
      #pragma unroll
      for (int o = 32; o > 0; o >>= 1){
        float ov = __shfl_xor(bv, o); int oi = __shfl_xor(bi, o);
        if (ov > bv || (ov == bv && oi < bi)){ bv = ov; bi = oi; }
      }
      if (tid == 0){
        int a = bi;
        int sop = stack_map[a], bop = buffer_map[a];
        if (spos == 0 && sop == -1) sop = 0;
        if (spos >= S1 - 1 && sop == 1) sop = 0;
        if (bposc == 0 && bop == -1) bop = 0;
        int push  = (sop == 1) ? 1 : 0;
        int widx  = (spos + 1 < S1 - 1) ? spos + 1 : S1 - 1;
        int sposn = spos + sop;
        int bposn = bposc + bop;
        int ne    = (bposn > 0) ? 1 : 0;
        int gidx  = bposn - 1; if (gidx < 0) gidx = 0; if (gidx > SEQ - 1) gidx = SEQ - 1;
        ctl[3] = a; ctl[4] = push; ctl[5] = widx; ctl[6] = sposn;
        ctl[7] = bposn; ctl[8] = ne; ctl[9] = gidx;
      }
    }
    __syncthreads();

    // D: z matvecs, coalesced. threads 0-255: st rows; 256-511: hist rows.
    {
      const int a = ctl[3];
      const int grp = tid >> 8, lt = tid & 255;
      const float* Wt = grp ? Wt_hi : Wt_st;                 // [256][1024]
      const float* xv = grp ? ahl : (stackh + spos*H);
      const float* av = grp ? (histxz + (size_t)a*G4)
                            : (st_zx + ((size_t)b*(SEQ+1) + sinc)*G4);
      float a0 = 0.f, a1 = 0.f, a2 = 0.f, a3 = 0.f;
      for (int c = 0; c < H; ++c){
        float4 w = ((const float4*)(Wt + (size_t)c*G4))[lt];
        float x = xv[c];
        a0 += w.x*x; a1 += w.y*x; a2 += w.z*x; a3 += w.w*x;
      }
      float4 ad = ((const float4*)av)[lt];
      float* dst = grp ? (u1 + G4) : u1;
      ((float4*)dst)[lt] = make_float4(a0+ad.x, a1+ad.y, a2+ad.z, a3+ad.w);
    }
    __syncthreads();

    // E: gates + state commit
    {
      const int push = ctl[4], widx = ctl[5], sposn = ctl[6];
      const int ne = ctl[8], gidx = ctl[9];
      const float* zst = u1;
      const float* zhi = u1 + G4;
      if (tid < H){
        float gi = zst[tid], gf = zst[H+tid], gg = zst[2*H+tid], go = zst[3*H+tid];
        float ctop = scst[((size_t)b*S1 + spos)*H + tid];
        float c2 = sigf(gf)*ctop + sigf(gi)*tanhf(gg);
        float h2 = sigf(go)*tanhf(c2);
        if (push){
          stackh[widx*H + tid] = h2;
          scst[((size_t)b*S1 + widx)*H + tid] = c2;
        }
        bstate[tid] = ne ? bufh[((size_t)b*SEQ + gidx)*H + tid] : h0l[tid];
      } else {
        int hh = tid - H;
        float gi = zhi[hh], gf = zhi[H+hh], gg = zhi[2*H+hh], go = zhi[3*H+hh];
        float c2 = sigf(gf)*acl[hh] + sigf(gi)*tanhf(gg);
        float h2 = sigf(go)*tanhf(c2);
        acl[hh] = c2; ahl[hh] = h2;
      }
      if (tid == 0){
        ctl[0] = sposn; ctl[1] = ctl[7]; ctl[2] = ne ? gidx : SEQ;
      }
    }
    __syncthreads();
  }
}

extern "C" void kernel_launch(void* const* d_in, const int* in_sizes, int n_in,
                              void* d_out, int out_size, void* d_ws, size_t ws_size,
                              hipStream_t stream){
  (void)in_sizes; (void)n_in; (void)out_size; (void)ws_size;
  const int*   tokens    = (const int*)  d_in[0];
  const float* word_emb  = (const float*)d_in[1];
  const float* compose_W = (const float*)d_in[2];
  const float* compose_b = (const float*)d_in[3];
  const float* h0        = (const float*)d_in[4];
  const float* c0        = (const float*)d_in[5];
  const float* pb_Wih    = (const float*)d_in[6];
  const float* pb_Whh    = (const float*)d_in[7];
  const float* pb_bih    = (const float*)d_in[8];
  const float* pb_bhh    = (const float*)d_in[9];
  const float* st_Wih    = (const float*)d_in[10];
  const float* st_Whh    = (const float*)d_in[11];
  const float* st_bih    = (const float*)d_in[12];
  const float* st_bhh    = (const float*)d_in[13];
  const float* hist_Wih  = (const float*)d_in[14];
  const float* hist_Whh  = (const float*)d_in[15];
  const float* hist_bih  = (const float*)d_in[16];
  const float* hist_bhh  = (const float*)d_in[17];
  const float* sum_W     = (const float*)d_in[18];
  const float* sum_b     = (const float*)d_in[19];
  const float* act_W     = (const float*)d_in[20];
  const float* act_b     = (const float*)d_in[21];
  const float* action_emb= (const float*)d_in[22];
  const int*   stack_map = (const int*)  d_in[23];
  const int*   buffer_map= (const int*)  d_in[24];

  float* ws     = (float*)d_ws;
  float* pb_zx  = ws;                                  // 128*64*1024
  float* st_zx  = pb_zx + (size_t)NB*SEQ*G4;           // 128*65*1024
  float* bufh   = st_zx + (size_t)NB*(SEQ+1)*G4;       // 128*64*256
  float* scst   = bufh  + (size_t)NB*SEQ*H;            // 128*41*256
  float* histxz = scst  + (size_t)NB*S1*H;             // 64*1024
  float* Wt_pb  = histxz + (size_t)NA*G4;              // [256][1024]
  float* Wt_st  = Wt_pb  + (size_t)H*G4;
  float* Wt_hi  = Wt_st  + (size_t)H*G4;
  float* Wt_sum = Wt_hi  + (size_t)H*G4;               // [768][256]
  float* Wt_act = Wt_sum + (size_t)768*H;              // [256][64]
  float* Wt_pbih= Wt_act + (size_t)H*NA;               // [128][1024]
  float* Wt_stih= Wt_pbih+ (size_t)DIN*G4;             // [128][1024]
  float* Wt_cmp = Wt_stih+ (size_t)DIN*G4;             // [256][128]

  dim3 blk(32, 8);
  transpose_k<<<dim3(256/32, 1024/32), blk, 0, stream>>>(pb_Whh,   Wt_pb,  1024, 256);
  transpose_k<<<dim3(256/32, 1024/32), blk, 0, stream>>>(st_Whh,   Wt_st,  1024, 256);
  transpose_k<<<dim3(256/32, 1024/32), blk, 0, stream>>>(hist_Whh, Wt_hi,  1024, 256);
  transpose_k<<<dim3(768/32,  256/32), blk, 0, stream>>>(sum_W,    Wt_sum,  256, 768);
  transpose_k<<<dim3(256/32,   64/32), blk, 0, stream>>>(act_W,    Wt_act,   64, 256);
  transpose_k<<<dim3(128/32, 1024/32), blk, 0, stream>>>(pb_Wih,   Wt_pbih,1024, 128);
  transpose_k<<<dim3(128/32, 1024/32), blk, 0, stream>>>(st_Wih,   Wt_stih,1024, 128);
  transpose_k<<<dim3(256/32,  128/32), blk, 0, stream>>>(compose_W,Wt_cmp,  128, 256);
  hist_proj_kernel<<<dim3(NA), dim3(256), 0, stream>>>(hist_Wih, hist_bih, hist_bhh,
                                                       action_emb, histxz);

  parser_kernel<<<dim3(NB), dim3(512), 0, stream>>>(tokens, word_emb, Wt_cmp, compose_b,
      h0, c0, Wt_pbih, Wt_pb, pb_bih, pb_bhh, Wt_stih, Wt_st, st_bih, st_bhh,
      Wt_hi, Wt_sum, sum_b, Wt_act, act_b, stack_map, buffer_map,
      histxz, pb_zx, st_zx, bufh, scst, (float*)d_out);
}